// Round 1
// baseline (23911.270 us; speedup 1.0000x reference)
//
#include <hip/hip_runtime.h>
#include <cmath>

// ViT backbone, fp32 throughout (precision anchor for top-k stability).
// D=768, H=12, DH=64, NL=12, B=32, L=197 (main) / 101 (last block), k=100.

#define NHEAD 12

// ---------------- generic tiled GEMM: C = A(MxK) @ B(KxN) + bias [+R] [gelu] ----------------
// OP 0: C = acc + bias
// OP 1: C = acc + bias + R   (residual)
// OP 2: C = gelu(acc + bias) (exact erf gelu)
template<int OP>
__global__ __launch_bounds__(256) void gemm_k(
    const float* __restrict__ A, const float* __restrict__ B,
    const float* __restrict__ bias, const float* __restrict__ R,
    float* __restrict__ C, int M, int N, int K, int lda, int ldb, int ldc)
{
    __shared__ float As[16][132];
    __shared__ float Bs[16][132];
    const int tid = threadIdx.x;
    const int row0 = blockIdx.y * 128, col0 = blockIdx.x * 128;
    const int tx = tid & 15, ty = tid >> 4;
    float acc[8][8];
#pragma unroll
    for (int i = 0; i < 8; ++i)
#pragma unroll
        for (int j = 0; j < 8; ++j) acc[i][j] = 0.f;

    for (int k0 = 0; k0 < K; k0 += 16) {
#pragma unroll
        for (int it = 0; it < 2; ++it) {
            int idx = tid + it * 256;
            int r = idx >> 2;
            int c = (idx & 3) << 2;
            float4 v = make_float4(0.f, 0.f, 0.f, 0.f);
            int gr = row0 + r;
            if (gr < M) v = *(const float4*)(A + (size_t)gr * lda + k0 + c);
            As[c + 0][r] = v.x; As[c + 1][r] = v.y; As[c + 2][r] = v.z; As[c + 3][r] = v.w;
        }
#pragma unroll
        for (int it = 0; it < 2; ++it) {
            int idx = tid + it * 256;
            int r = idx >> 5;
            int c = (idx & 31) << 2;
            float4 v = make_float4(0.f, 0.f, 0.f, 0.f);
            int gc = col0 + c;
            if (gc < N) v = *(const float4*)(B + (size_t)(k0 + r) * ldb + gc);
            *(float4*)&Bs[r][c] = v;
        }
        __syncthreads();
#pragma unroll
        for (int kk = 0; kk < 16; ++kk) {
            float a[8], b[8];
            *(float4*)&a[0] = *(const float4*)&As[kk][ty * 8];
            *(float4*)&a[4] = *(const float4*)&As[kk][ty * 8 + 4];
            *(float4*)&b[0] = *(const float4*)&Bs[kk][tx * 8];
            *(float4*)&b[4] = *(const float4*)&Bs[kk][tx * 8 + 4];
#pragma unroll
            for (int i = 0; i < 8; ++i)
#pragma unroll
                for (int j = 0; j < 8; ++j) acc[i][j] += a[i] * b[j];
        }
        __syncthreads();
    }
#pragma unroll
    for (int i = 0; i < 8; ++i) {
        int gr = row0 + ty * 8 + i;
        if (gr >= M) continue;
#pragma unroll
        for (int j = 0; j < 8; ++j) {
            int gc = col0 + tx * 8 + j;
            if (gc >= N) continue;
            float v = acc[i][j] + bias[gc];
            if (OP == 1) v += R[(size_t)gr * ldc + gc];
            if (OP == 2) v = 0.5f * v * (1.f + erff(v * 0.70710678118654752f));
            C[(size_t)gr * ldc + gc] = v;
        }
    }
}

// ---------------- LayerNorm: y = (x-m)/sqrt(v+eps)*s + b, row = 768 ----------------
__global__ __launch_bounds__(256) void ln_k(
    const float* __restrict__ x, const float* __restrict__ s,
    const float* __restrict__ bb, float* __restrict__ y)
{
    int r = blockIdx.x;
    int tid = threadIdx.x;
    const float* xr = x + (size_t)r * 768;
    float v0 = xr[tid], v1 = xr[tid + 256], v2 = xr[tid + 512];
    __shared__ float red[256];
    red[tid] = v0 + v1 + v2;
    __syncthreads();
    for (int off = 128; off > 0; off >>= 1) {
        if (tid < off) red[tid] += red[tid + off];
        __syncthreads();
    }
    float m = red[0] / 768.f;
    __syncthreads();
    float d0 = v0 - m, d1 = v1 - m, d2 = v2 - m;
    red[tid] = d0 * d0 + d1 * d1 + d2 * d2;
    __syncthreads();
    for (int off = 128; off > 0; off >>= 1) {
        if (tid < off) red[tid] += red[tid + off];
        __syncthreads();
    }
    float inv = 1.f / sqrtf(red[0] / 768.f + 1e-6f);
    float* yr = y + (size_t)r * 768;
    yr[tid]       = d0 * inv * s[tid]       + bb[tid];
    yr[tid + 256] = d1 * inv * s[tid + 256] + bb[tid + 256];
    yr[tid + 512] = d2 * inv * s[tid + 512] + bb[tid + 512];
}

// ---------------- attention: scores + softmax (8 query rows per block) ----------------
__global__ __launch_bounds__(256) void attn_scores8_k(
    const float* __restrict__ qkv, float* __restrict__ probs, int L)
{
    int qi0 = blockIdx.x * 8, h = blockIdx.y, b = blockIdx.z;
    int tid = threadIdx.x;
    int nq = L - qi0; if (nq > 8) nq = 8;
    __shared__ float qs[8][64];
    __shared__ float ps[8][208];
    for (int idx = tid; idx < 512; idx += 256) {
        int r = idx >> 6, d = idx & 63;
        qs[r][d] = (r < nq) ? qkv[((size_t)(b * L + qi0 + r)) * 2304 + h * 64 + d] : 0.f;
    }
    __syncthreads();
    for (int k2 = tid; k2 < L; k2 += 256) {
        const float* kr = qkv + ((size_t)(b * L + k2)) * 2304 + 768 + h * 64;
        float a[8] = {0.f,0.f,0.f,0.f,0.f,0.f,0.f,0.f};
        for (int d = 0; d < 64; d += 4) {
            float4 kv = *(const float4*)(kr + d);
#pragma unroll
            for (int r = 0; r < 8; ++r) {
                a[r] += qs[r][d] * kv.x + qs[r][d + 1] * kv.y + qs[r][d + 2] * kv.z + qs[r][d + 3] * kv.w;
            }
        }
#pragma unroll
        for (int r = 0; r < 8; ++r) ps[r][k2] = a[r] * 0.125f;
    }
    __syncthreads();
    int wid = tid >> 6, lane = tid & 63;
    for (int r = wid; r < nq; r += 4) {
        float m = -1e30f;
        for (int k2 = lane; k2 < L; k2 += 64) m = fmaxf(m, ps[r][k2]);
#pragma unroll
        for (int off = 32; off > 0; off >>= 1) m = fmaxf(m, __shfl_xor(m, off, 64));
        float sum = 0.f;
        for (int k2 = lane; k2 < L; k2 += 64) {
            float e = expf(ps[r][k2] - m);
            ps[r][k2] = e;
            sum += e;
        }
#pragma unroll
        for (int off = 32; off > 0; off >>= 1) sum += __shfl_xor(sum, off, 64);
        float inv = 1.f / sum;
        float* pr = probs + (((size_t)(b * NHEAD + h) * L + qi0 + r)) * L;
        for (int k2 = lane; k2 < L; k2 += 64) pr[k2] = ps[r][k2] * inv;
    }
}

// ---------------- attention: O = P @ V (8 query rows per block, 64 threads = head dim) ----------------
__global__ __launch_bounds__(64) void attn_pv8_k(
    const float* __restrict__ qkv, const float* __restrict__ probs,
    float* __restrict__ o, int L)
{
    int qi0 = blockIdx.x * 8, h = blockIdx.y, b = blockIdx.z;
    int lane = threadIdx.x;
    int nq = L - qi0; if (nq > 8) nq = 8;
    __shared__ float ps[8][208];
    for (int r = 0; r < nq; ++r) {
        const float* pr = probs + (((size_t)(b * NHEAD + h) * L + qi0 + r)) * L;
        for (int k2 = lane; k2 < L; k2 += 64) ps[r][k2] = pr[k2];
    }
    __syncthreads();
    float acc[8] = {0.f,0.f,0.f,0.f,0.f,0.f,0.f,0.f};
    const float* vb = qkv + (size_t)b * L * 2304 + 1536 + h * 64 + lane;
    for (int k2 = 0; k2 < L; ++k2) {
        float vv = vb[(size_t)k2 * 2304];
#pragma unroll
        for (int r = 0; r < 8; ++r) acc[r] += ps[r][k2] * vv;
    }
    for (int r = 0; r < nq; ++r)
        o[((size_t)(b * L + qi0 + r)) * 768 + h * 64 + lane] = acc[r];
}

// ---------------- patch embed helpers ----------------
__global__ __launch_bounds__(256) void transpose_k(const float* __restrict__ w, float* __restrict__ wt)
{
    int i = blockIdx.x * 256 + threadIdx.x; // over 768*768
    int d = i / 768, k2 = i % 768;
    wt[(size_t)k2 * 768 + d] = w[i];
}

__global__ __launch_bounds__(256) void gather_k(const float* __restrict__ x, float* __restrict__ p)
{
    int n = blockIdx.x, b = blockIdx.y, tid = threadIdx.x;
    int hp = n / 14, wp = n % 14;
    float* dst = p + ((size_t)(b * 196 + n)) * 768;
    for (int e = tid; e < 768; e += 256) {
        int c = e >> 8, rem = e & 255, rr = rem >> 4, cc = rem & 15;
        dst[e] = x[((size_t)(b * 3 + c) * 224 + (hp * 16 + rr)) * 224 + wp * 16 + cc];
    }
}

__global__ __launch_bounds__(256) void embed_k(
    const float* __restrict__ tpatch, const float* __restrict__ cls,
    const float* __restrict__ pos, float* __restrict__ t)
{
    int m = blockIdx.x, b = blockIdx.y, tid = threadIdx.x;
    float* dst = t + ((size_t)(b * 197 + m)) * 768;
    if (m == 0) {
        for (int e = tid; e < 768; e += 256) dst[e] = cls[e] + pos[e];
    } else {
        const float* s2 = tpatch + ((size_t)(b * 196 + m - 1)) * 768;
        for (int e = tid; e < 768; e += 256) dst[e] = s2[e] + pos[(size_t)m * 768 + e];
    }
}

// ---------------- A_hat path (attention on raw t with layer-10 weights, q-row 0 only) ----------------
__global__ __launch_bounds__(256) void q0_k(
    const float* __restrict__ T, const float* __restrict__ W,
    const float* __restrict__ bq, float* __restrict__ q0)
{
    int b = blockIdx.x, tid = threadIdx.x;
    __shared__ float ys[768];
    const float* yr = T + (size_t)b * 197 * 768; // row 0 of batch b (raw t, NO layernorm!)
    ys[tid] = yr[tid]; ys[tid + 256] = yr[tid + 256]; ys[tid + 512] = yr[tid + 512];
    __syncthreads();
    for (int d = tid; d < 768; d += 256) {
        float acc = bq[d];
        for (int k2 = 0; k2 < 768; ++k2) acc += ys[k2] * W[(size_t)k2 * 2304 + d];
        q0[(size_t)b * 768 + d] = acc;
    }
}

__global__ __launch_bounds__(256) void ahat_k(
    const float* __restrict__ kmat, const float* __restrict__ q0,
    float* __restrict__ Ahat)
{
    int b = blockIdx.x, tid = threadIdx.x;
    __shared__ float qs[64];
    __shared__ float sc[256];
    __shared__ float red[256];
    __shared__ float ah[196];
    for (int j = tid; j < 196; j += 256) ah[j] = 0.f;
    for (int h = 0; h < NHEAD; ++h) {
        __syncthreads();
        if (tid < 64) qs[tid] = q0[(size_t)b * 768 + h * 64 + tid];
        __syncthreads();
        if (tid < 197) {
            const float* kr = kmat + ((size_t)(b * 197 + tid)) * 768 + h * 64;
            float acc = 0.f;
            for (int d = 0; d < 64; ++d) acc += qs[d] * kr[d];
            sc[tid] = acc * 0.125f;
        }
        __syncthreads();
        red[tid] = (tid < 197) ? sc[tid] : -1e30f;
        __syncthreads();
        for (int off = 128; off > 0; off >>= 1) {
            if (tid < off) red[tid] = fmaxf(red[tid], red[tid + off]);
            __syncthreads();
        }
        float m = red[0];
        __syncthreads();
        float e = 0.f;
        if (tid < 197) { e = expf(sc[tid] - m); sc[tid] = e; }
        red[tid] = e;
        __syncthreads();
        for (int off = 128; off > 0; off >>= 1) {
            if (tid < off) red[tid] += red[tid + off];
            __syncthreads();
        }
        float inv = 1.f / red[0];
        if (tid >= 1 && tid < 197) ah[tid - 1] += sc[tid] * inv;
    }
    __syncthreads();
    for (int j = tid; j < 196; j += 256) Ahat[(size_t)b * 196 + j] = ah[j];
}

__global__ __launch_bounds__(256) void zo_k(
    const float* __restrict__ t, const float* __restrict__ impw,
    const float* __restrict__ impb, const float* __restrict__ Ahat,
    float* __restrict__ O)
{
    int b = blockIdx.x, tid = threadIdx.x;
    __shared__ float w[768];
    w[tid] = impw[tid]; w[tid + 256] = impw[tid + 256]; w[tid + 512] = impw[tid + 512];
    __syncthreads();
    for (int j = tid; j < 196; j += 256) {
        const float* tr = t + ((size_t)(b * 197) + 1 + j) * 768;
        float acc = impb[0];
        for (int d = 0; d < 768; ++d) acc += tr[d] * w[d];
        float z = 1.f / (1.f + expf(-acc));
        float a = Ahat[(size_t)b * 196 + j];
        O[(size_t)b * 196 + j] = a + a * z;
    }
}

// exact jax.lax.top_k semantics: descending, ties -> lower index first
__global__ __launch_bounds__(256) void topk_k(const float* __restrict__ O, int* __restrict__ idx)
{
    int b = blockIdx.x, tid = threadIdx.x;
    __shared__ float s[196];
    if (tid < 196) s[tid] = O[(size_t)b * 196 + tid];
    __syncthreads();
    if (tid < 196) {
        float v = s[tid];
        int rank = 0;
        for (int i = 0; i < 196; ++i) {
            float u = s[i];
            rank += (u > v) || (u == v && i < tid);
        }
        if (rank < 100) idx[b * 100 + rank] = tid;
    }
}

__global__ __launch_bounds__(256) void build_k(
    const float* __restrict__ t, const float* __restrict__ pos,
    const int* __restrict__ idx, float* __restrict__ inp, float* __restrict__ tp)
{
    int m = blockIdx.x, b = blockIdx.y, tid = threadIdx.x;
    float* dst = inp + ((size_t)(b * 101 + m)) * 768;
    if (m == 0) {
        const float* tr = t + (size_t)b * 197 * 768;
        for (int e = tid; e < 768; e += 256) dst[e] = tr[e] + pos[e];
    } else {
        int j = idx[b * 100 + m - 1];
        const float* tr = t + ((size_t)(b * 197) + 1 + j) * 768;
        const float* pr = pos + (size_t)(1 + j) * 768;
        float* tpr = tp + ((size_t)(b * 100) + (m - 1)) * 768;
        for (int e = tid; e < 768; e += 256) {
            float val = tr[e];
            tpr[e] = val;
            dst[e] = val + pr[e];
        }
    }
}

// ---------------- host side ----------------
extern "C" void kernel_launch(void* const* d_in, const int* in_sizes, int n_in,
                              void* d_out, int out_size, void* d_ws, size_t ws_size,
                              hipStream_t stream)
{
    const float* x      = (const float*)d_in[0];
    const float* conv_w = (const float*)d_in[1];
    const float* conv_b = (const float*)d_in[2];
    const float* cls    = (const float*)d_in[3];
    const float* pos    = (const float*)d_in[4];
    const float* ln1_s  = (const float*)d_in[5];
    const float* ln1_b  = (const float*)d_in[6];
    const float* qkv_w  = (const float*)d_in[7];
    const float* qkv_b  = (const float*)d_in[8];
    const float* proj_w = (const float*)d_in[9];
    const float* proj_b = (const float*)d_in[10];
    const float* ln2_s  = (const float*)d_in[11];
    const float* ln2_b  = (const float*)d_in[12];
    const float* mlp_w1 = (const float*)d_in[13];
    const float* mlp_b1 = (const float*)d_in[14];
    const float* mlp_w2 = (const float*)d_in[15];
    const float* mlp_b2 = (const float*)d_in[16];
    const float* fln_s  = (const float*)d_in[17];
    const float* fln_b  = (const float*)d_in[18];
    const float* imp_w  = (const float*)d_in[19];
    const float* imp_b  = (const float*)d_in[20];

    float* ws = (float*)d_ws;
    const size_t SZ_T   = (size_t)32 * 197 * 768;   // 4,841,472
    const size_t SZ_QKV = (size_t)32 * 197 * 2304;  // 14,524,416
    const size_t SZ_H   = (size_t)32 * 197 * 3072;  // 19,365,888
    float* T    = ws;
    float* Y    = T + SZ_T;
    float* QKV  = Y + SZ_T;
    float* OB   = QKV + SZ_QKV;
    float* HB   = OB + SZ_T;
    float* WT   = HB + SZ_H;
    float* INP  = WT + (size_t)768 * 768;
    float* Q0   = INP + (size_t)32 * 101 * 768;
    float* AH   = Q0 + (size_t)32 * 768;
    float* OV   = AH + (size_t)32 * 196;
    int*   IDX  = (int*)(OV + (size_t)32 * 196);

    float* out0 = (float*)d_out;                        // (32,101,768)
    float* out1 = out0 + (size_t)32 * 101 * 768;        // top_patches (32,100,768)

    // ---- patch embed ----
    transpose_k<<<768 * 768 / 256, 256, 0, stream>>>(conv_w, WT);
    gather_k<<<dim3(196, 32), 256, 0, stream>>>(x, Y);
    gemm_k<0><<<dim3(6, 49), 256, 0, stream>>>(Y, WT, conv_b, nullptr, OB,
                                               6272, 768, 768, 768, 768, 768);
    embed_k<<<dim3(197, 32), 256, 0, stream>>>(OB, cls, pos, T);

    auto run_block = [&](float* X, int L, int i) {
        int M = 32 * L;
        int mtiles = (M + 127) / 128;
        int sblk = (L + 7) / 8;
        ln_k<<<M, 256, 0, stream>>>(X, ln1_s + i * 768, ln1_b + i * 768, Y);
        gemm_k<0><<<dim3(18, mtiles), 256, 0, stream>>>(
            Y, qkv_w + (size_t)i * 768 * 2304, qkv_b + (size_t)i * 2304, nullptr, QKV,
            M, 2304, 768, 768, 2304, 2304);
        attn_scores8_k<<<dim3(sblk, NHEAD, 32), 256, 0, stream>>>(QKV, HB, L);
        attn_pv8_k<<<dim3(sblk, NHEAD, 32), 64, 0, stream>>>(QKV, HB, OB, L);
        gemm_k<1><<<dim3(6, mtiles), 256, 0, stream>>>(
            OB, proj_w + (size_t)i * 768 * 768, proj_b + (size_t)i * 768, X, X,
            M, 768, 768, 768, 768, 768);
        ln_k<<<M, 256, 0, stream>>>(X, ln2_s + i * 768, ln2_b + i * 768, Y);
        gemm_k<2><<<dim3(24, mtiles), 256, 0, stream>>>(
            Y, mlp_w1 + (size_t)i * 768 * 3072, mlp_b1 + (size_t)i * 3072, nullptr, HB,
            M, 3072, 768, 768, 3072, 3072);
        gemm_k<1><<<dim3(6, mtiles), 256, 0, stream>>>(
            HB, mlp_w2 + (size_t)i * 3072 * 768, mlp_b2 + (size_t)i * 768, X, X,
            M, 768, 3072, 3072, 768, 768);
    };

    for (int i = 0; i < 11; ++i) run_block(T, 197, i);

    // ---- A_hat: attention weights of layer-10 applied to RAW t (no LN), query row 0 only ----
    // kmat = t @ Wk[10] + bk[10]  -> stored in QKV buffer as (32*197, 768)
    gemm_k<0><<<dim3(6, 50), 256, 0, stream>>>(
        T, qkv_w + (size_t)10 * 768 * 2304 + 768, qkv_b + (size_t)10 * 2304 + 768,
        nullptr, QKV, 6304, 768, 768, 768, 2304, 768);
    q0_k<<<32, 256, 0, stream>>>(T, qkv_w + (size_t)10 * 768 * 2304,
                                 qkv_b + (size_t)10 * 2304, Q0);
    ahat_k<<<32, 256, 0, stream>>>(QKV, Q0, AH);
    zo_k<<<32, 256, 0, stream>>>(T, imp_w, imp_b, AH, OV);
    topk_k<<<32, 256, 0, stream>>>(OV, IDX);
    build_k<<<dim3(101, 32), 256, 0, stream>>>(T, pos, IDX, INP, out1);

    // ---- last block on gathered tokens (L=101, layer 11) ----
    run_block(INP, 101, 11);

    // ---- final LN -> out0 ----
    ln_k<<<32 * 101, 256, 0, stream>>>(INP, fln_s, fln_b, out0);

    (void)in_sizes; (void)n_in; (void)out_size; (void)ws_size;
}

// Round 4
// 18806.459 us; speedup vs baseline: 1.2714x; 1.2714x over previous
//
#include <hip/hip_runtime.h>
#include <cmath>

// ViT backbone. GEMMs via bf16x6 (triple-split) error-compensated MFMA (16x16x32),
// per-product error ~2^-25 (better than fp32 per-op rounding) so top-k order is
// preserved vs the fp32 reference. Rest fp32.
// D=768, H=12, DH=64, NL=12, B=32, L=197 (main) / 101 (last block), k=100.

#define NHEAD 12

typedef __attribute__((ext_vector_type(8))) short short8;
typedef __attribute__((ext_vector_type(4))) float f32x4;

// ---- RN bf16 with exact residual ----
__device__ __forceinline__ short rnb(float x, float& rem) {
    unsigned u = __float_as_uint(x);
    unsigned hr = (u + 0x7FFFu + ((u >> 16) & 1u)) >> 16;
    rem = x - __uint_as_float(hr << 16);
    return (short)hr;
}
// x = h + m + l (all bf16), dropped error ~2^-27 |x|
__device__ __forceinline__ void split3(float x, short& h, short& m, short& l) {
    float r1, r2, r3;
    h = rnb(x, r1);
    m = rnb(r1, r2);
    l = rnb(r2, r3);
}

__device__ __forceinline__ void ldg2lds(const void* g, void* l) {
    __builtin_amdgcn_global_load_lds((const __attribute__((address_space(1))) void*)g,
                                     (__attribute__((address_space(3))) void*)l, 16, 0, 0);
}

// ---------------- MFMA GEMM: C(MxN) = A(MxK) @ Bt(NxK)^T + bias [+R] [gelu] ----------------
// A as bf16 triple (Ah,Am,Al) row-major [M][K]; B as bf16 triple [N][K] (pre-transposed).
// OP 0: C = acc + bias                 (fp32 out)
// OP 1: C = acc + bias + R             (fp32 out, residual)
// OP 2: C* = split3(gelu(acc+bias))    (bf16-triple out)
template<int OP>
__global__ __launch_bounds__(256, 2) void mgemm_k(
    const short* __restrict__ Ah, const short* __restrict__ Am, const short* __restrict__ Al,
    const short* __restrict__ Bh, const short* __restrict__ Bm, const short* __restrict__ Bl,
    const float* __restrict__ bias, const float* __restrict__ R,
    float* __restrict__ C, short* __restrict__ Ch, short* __restrict__ Cm, short* __restrict__ Cl,
    int M, int N, int K, int ldc)
{
    __shared__ short sA[3][128 * 32];
    __shared__ short sB[3][128 * 32];
    const int tid = threadIdx.x;
    const int wid = tid >> 6, lane = tid & 63;
    const int wm = wid >> 1, wn = wid & 1;
    const int quad = lane >> 4, l15 = lane & 15;
    const int row0 = blockIdx.y * 128, col0 = blockIdx.x * 128;

    f32x4 acc[4][4];
#pragma unroll
    for (int i = 0; i < 4; ++i)
#pragma unroll
        for (int j = 0; j < 4; ++j) { acc[i][j][0] = 0.f; acc[i][j][1] = 0.f; acc[i][j][2] = 0.f; acc[i][j][3] = 0.f; }

    const int srow = lane >> 2;          // 0..15
    const int schunk = (lane & 3) * 8;   // k-element offset of this lane's 16B

    for (int k0 = 0; k0 < K; k0 += 32) {
#pragma unroll
        for (int rnd = 0; rnd < 2; ++rnd) {
            int m = rnd * 64 + wid * 16 + srow;            // row within tile, 0..127
            int gr = row0 + m; if (gr > M - 1) gr = M - 1; // clamp (stores masked later)
            int gn = col0 + m;                             // N always multiple of 128
            size_t ao = (size_t)gr * K + k0 + schunk;
            size_t bo = (size_t)gn * K + k0 + schunk;
            int lofs = (rnd * 64 + wid * 16) * 32;
            ldg2lds(Ah + ao, &sA[0][lofs]);
            ldg2lds(Am + ao, &sA[1][lofs]);
            ldg2lds(Al + ao, &sA[2][lofs]);
            ldg2lds(Bh + bo, &sB[0][lofs]);
            ldg2lds(Bm + bo, &sB[1][lofs]);
            ldg2lds(Bl + bo, &sB[2][lofs]);
        }
        __syncthreads();

        short8 a[4][3];
#pragma unroll
        for (int i = 0; i < 4; ++i) {
            int m = wm * 64 + i * 16 + l15;
#pragma unroll
            for (int p = 0; p < 3; ++p)
                a[i][p] = *(const short8*)&sA[p][m * 32 + quad * 8];
        }
#pragma unroll
        for (int j = 0; j < 4; ++j) {
            int n = wn * 64 + j * 16 + l15;
            short8 bh = *(const short8*)&sB[0][n * 32 + quad * 8];
            short8 bm = *(const short8*)&sB[1][n * 32 + quad * 8];
            short8 bl = *(const short8*)&sB[2][n * 32 + quad * 8];
#pragma unroll
            for (int i = 0; i < 4; ++i) {
                // small terms first, then large (chained fp32 accumulate)
                acc[i][j] = __builtin_amdgcn_mfma_f32_16x16x32_bf16(a[i][2], bh, acc[i][j], 0, 0, 0); // l*h
                acc[i][j] = __builtin_amdgcn_mfma_f32_16x16x32_bf16(a[i][0], bl, acc[i][j], 0, 0, 0); // h*l
                acc[i][j] = __builtin_amdgcn_mfma_f32_16x16x32_bf16(a[i][1], bm, acc[i][j], 0, 0, 0); // m*m
                acc[i][j] = __builtin_amdgcn_mfma_f32_16x16x32_bf16(a[i][1], bh, acc[i][j], 0, 0, 0); // m*h
                acc[i][j] = __builtin_amdgcn_mfma_f32_16x16x32_bf16(a[i][0], bm, acc[i][j], 0, 0, 0); // h*m
                acc[i][j] = __builtin_amdgcn_mfma_f32_16x16x32_bf16(a[i][0], bh, acc[i][j], 0, 0, 0); // h*h
            }
        }
        __syncthreads();
    }

#pragma unroll
    for (int i = 0; i < 4; ++i) {
#pragma unroll
        for (int r = 0; r < 4; ++r) {
            int gr = row0 + wm * 64 + i * 16 + quad * 4 + r;
            if (gr >= M) continue;
#pragma unroll
            for (int j = 0; j < 4; ++j) {
                int gc = col0 + wn * 64 + j * 16 + l15;
                float v = acc[i][j][r] + bias[gc];
                if (OP == 1) v += R[(size_t)gr * ldc + gc];
                if (OP == 2) {
                    v = 0.5f * v * (1.f + erff(v * 0.70710678118654752f));
                    short h, m, l; split3(v, h, m, l);
                    size_t o = (size_t)gr * ldc + gc;
                    Ch[o] = h; Cm[o] = m; Cl[o] = l;
                } else {
                    C[(size_t)gr * ldc + gc] = v;
                }
            }
        }
    }
}

// ---------------- weight transpose + split: W[K][N] (ld) -> triple [N][K] ----------------
__global__ __launch_bounds__(256) void ts_k(
    const float* __restrict__ W, int ld,
    short* __restrict__ Bh, short* __restrict__ Bm, short* __restrict__ Bl, int K, int N)
{
    __shared__ float tile[32][33];
    int n0 = blockIdx.x * 32, k0 = blockIdx.y * 32;
    int c = threadIdx.x & 31, r0 = threadIdx.x >> 5;
    for (int rr = r0; rr < 32; rr += 8)
        tile[rr][c] = W[(size_t)(k0 + rr) * ld + n0 + c];
    __syncthreads();
    for (int rr = r0; rr < 32; rr += 8) {
        float v = tile[c][rr];  // = W[k0+c][n0+rr]
        short h, m, l; split3(v, h, m, l);
        size_t o = (size_t)(n0 + rr) * K + k0 + c;
        Bh[o] = h; Bm[o] = m; Bl[o] = l;
    }
}

// ---------------- elementwise split (conv_w already [n][k]; also T -> triple) ----------------
__global__ __launch_bounds__(256) void esplit_k(
    const float* __restrict__ X, short* __restrict__ H, short* __restrict__ Mm,
    short* __restrict__ Lo, int n)
{
    int i = blockIdx.x * 256 + threadIdx.x;
    if (i < n) { short h, m, l; split3(X[i], h, m, l); H[i] = h; Mm[i] = m; Lo[i] = l; }
}

// ---------------- LayerNorm row=768; MODE0: fp32 out, MODE1: bf16-triple out ----------------
template<int MODE>
__global__ __launch_bounds__(256) void ln_k(
    const float* __restrict__ x, const float* __restrict__ s,
    const float* __restrict__ bb, float* __restrict__ y,
    short* __restrict__ yh, short* __restrict__ ym, short* __restrict__ yl)
{
    int r = blockIdx.x;
    int tid = threadIdx.x;
    const float* xr = x + (size_t)r * 768;
    float v0 = xr[tid], v1 = xr[tid + 256], v2 = xr[tid + 512];
    __shared__ float red[256];
    red[tid] = v0 + v1 + v2;
    __syncthreads();
    for (int off = 128; off > 0; off >>= 1) {
        if (tid < off) red[tid] += red[tid + off];
        __syncthreads();
    }
    float m = red[0] / 768.f;
    __syncthreads();
    float d0 = v0 - m, d1 = v1 - m, d2 = v2 - m;
    red[tid] = d0 * d0 + d1 * d1 + d2 * d2;
    __syncthreads();
    for (int off = 128; off > 0; off >>= 1) {
        if (tid < off) red[tid] += red[tid + off];
        __syncthreads();
    }
    float inv = 1.f / sqrtf(red[0] / 768.f + 1e-6f);
    float o0 = d0 * inv * s[tid] + bb[tid];
    float o1 = d1 * inv * s[tid + 256] + bb[tid + 256];
    float o2 = d2 * inv * s[tid + 512] + bb[tid + 512];
    if (MODE == 0) {
        float* yr = y + (size_t)r * 768;
        yr[tid] = o0; yr[tid + 256] = o1; yr[tid + 512] = o2;
    } else {
        size_t base = (size_t)r * 768;
        short h, mm2, l;
        split3(o0, h, mm2, l); yh[base + tid] = h;       ym[base + tid] = mm2;       yl[base + tid] = l;
        split3(o1, h, mm2, l); yh[base + tid + 256] = h; ym[base + tid + 256] = mm2; yl[base + tid + 256] = l;
        split3(o2, h, mm2, l); yh[base + tid + 512] = h; ym[base + tid + 512] = mm2; yl[base + tid + 512] = l;
    }
}

// ---------------- fused attention: scores + softmax + PV, 8 q-rows per block ----------------
__global__ __launch_bounds__(256) void attn_k(
    const float* __restrict__ qkv,
    short* __restrict__ oh, short* __restrict__ om, short* __restrict__ ol, int L)
{
    int qi0 = blockIdx.x * 8, h = blockIdx.y, b = blockIdx.z;
    int tid = threadIdx.x;
    int nq = L - qi0; if (nq > 8) nq = 8;
    __shared__ float qs[8][64];
    __shared__ float ps[8][208];
    for (int idx = tid; idx < 512; idx += 256) {
        int r = idx >> 6, d = idx & 63;
        qs[r][d] = (r < nq) ? qkv[((size_t)(b * L + qi0 + r)) * 2304 + h * 64 + d] : 0.f;
    }
    __syncthreads();
    for (int k2 = tid; k2 < L; k2 += 256) {
        const float* kr = qkv + ((size_t)(b * L + k2)) * 2304 + 768 + h * 64;
        float a[8] = {0.f,0.f,0.f,0.f,0.f,0.f,0.f,0.f};
        for (int d = 0; d < 64; d += 4) {
            float4 kv = *(const float4*)(kr + d);
#pragma unroll
            for (int r = 0; r < 8; ++r)
                a[r] += qs[r][d] * kv.x + qs[r][d + 1] * kv.y + qs[r][d + 2] * kv.z + qs[r][d + 3] * kv.w;
        }
#pragma unroll
        for (int r = 0; r < 8; ++r) ps[r][k2] = a[r] * 0.125f;
    }
    __syncthreads();
    int wid = tid >> 6, lane = tid & 63;
    for (int r = wid; r < nq; r += 4) {
        float m = -1e30f;
        for (int k2 = lane; k2 < L; k2 += 64) m = fmaxf(m, ps[r][k2]);
#pragma unroll
        for (int off = 32; off > 0; off >>= 1) m = fmaxf(m, __shfl_xor(m, off, 64));
        float sum = 0.f;
        for (int k2 = lane; k2 < L; k2 += 64) {
            float e = expf(ps[r][k2] - m);
            ps[r][k2] = e;
            sum += e;
        }
#pragma unroll
        for (int off = 32; off > 0; off >>= 1) sum += __shfl_xor(sum, off, 64);
        float inv = 1.f / sum;
        for (int k2 = lane; k2 < L; k2 += 64) ps[r][k2] *= inv;
    }
    __syncthreads();
    int d = tid & 63, rs = tid >> 6;
    float a0 = 0.f, a1 = 0.f;
    const float* vb = qkv + (size_t)b * L * 2304 + 1536 + h * 64 + d;
    for (int k2 = 0; k2 < L; ++k2) {
        float vv = vb[(size_t)k2 * 2304];
        a0 += ps[rs][k2] * vv;
        a1 += ps[rs + 4][k2] * vv;
    }
    if (rs < nq) {
        short hh, mm2, ll; split3(a0, hh, mm2, ll);
        size_t o = ((size_t)(b * L + qi0 + rs)) * 768 + h * 64 + d;
        oh[o] = hh; om[o] = mm2; ol[o] = ll;
    }
    if (rs + 4 < nq) {
        short hh, mm2, ll; split3(a1, hh, mm2, ll);
        size_t o = ((size_t)(b * L + qi0 + rs + 4)) * 768 + h * 64 + d;
        oh[o] = hh; om[o] = mm2; ol[o] = ll;
    }
}

// ---------------- patch embed helpers ----------------
__global__ __launch_bounds__(256) void gather_k(
    const float* __restrict__ x,
    short* __restrict__ ph, short* __restrict__ pm, short* __restrict__ pl)
{
    int n = blockIdx.x, b = blockIdx.y, tid = threadIdx.x;
    int hp = n / 14, wp = n % 14;
    size_t base = ((size_t)(b * 196 + n)) * 768;
    for (int e = tid; e < 768; e += 256) {
        int c = e >> 8, rem = e & 255, rr = rem >> 4, cc = rem & 15;
        float v = x[((size_t)(b * 3 + c) * 224 + (hp * 16 + rr)) * 224 + wp * 16 + cc];
        short h, m, l; split3(v, h, m, l);
        ph[base + e] = h; pm[base + e] = m; pl[base + e] = l;
    }
}

__global__ __launch_bounds__(256) void embed_k(
    const float* __restrict__ tpatch, const float* __restrict__ cls,
    const float* __restrict__ pos, float* __restrict__ t)
{
    int m = blockIdx.x, b = blockIdx.y, tid = threadIdx.x;
    float* dst = t + ((size_t)(b * 197 + m)) * 768;
    if (m == 0) {
        for (int e = tid; e < 768; e += 256) dst[e] = cls[e] + pos[e];
    } else {
        const float* s2 = tpatch + ((size_t)(b * 196 + m - 1)) * 768;
        for (int e = tid; e < 768; e += 256) dst[e] = s2[e] + pos[(size_t)m * 768 + e];
    }
}

// ---------------- A_hat path (layer-10 attention on RAW t, q-row 0 only) ----------------
__global__ __launch_bounds__(256) void q0_k(
    const float* __restrict__ T, const float* __restrict__ W,
    const float* __restrict__ bq, float* __restrict__ q0)
{
    int b = blockIdx.x, tid = threadIdx.x;
    __shared__ float ys[768];
    const float* yr = T + (size_t)b * 197 * 768;
    ys[tid] = yr[tid]; ys[tid + 256] = yr[tid + 256]; ys[tid + 512] = yr[tid + 512];
    __syncthreads();
    for (int d = tid; d < 768; d += 256) {
        float acc = bq[d];
        for (int k2 = 0; k2 < 768; ++k2) acc += ys[k2] * W[(size_t)k2 * 2304 + d];
        q0[(size_t)b * 768 + d] = acc;
    }
}

__global__ __launch_bounds__(256) void ahat_k(
    const float* __restrict__ kmat, const float* __restrict__ q0,
    float* __restrict__ Ahat)
{
    int b = blockIdx.x, tid = threadIdx.x;
    __shared__ float qs[64];
    __shared__ float sc[256];
    __shared__ float red[256];
    __shared__ float ah[196];
    for (int j = tid; j < 196; j += 256) ah[j] = 0.f;
    for (int h = 0; h < NHEAD; ++h) {
        __syncthreads();
        if (tid < 64) qs[tid] = q0[(size_t)b * 768 + h * 64 + tid];
        __syncthreads();
        if (tid < 197) {
            const float* kr = kmat + ((size_t)(b * 197 + tid)) * 768 + h * 64;
            float acc = 0.f;
            for (int d = 0; d < 64; ++d) acc += qs[d] * kr[d];
            sc[tid] = acc * 0.125f;
        }
        __syncthreads();
        red[tid] = (tid < 197) ? sc[tid] : -1e30f;
        __syncthreads();
        for (int off = 128; off > 0; off >>= 1) {
            if (tid < off) red[tid] = fmaxf(red[tid], red[tid + off]);
            __syncthreads();
        }
        float m = red[0];
        __syncthreads();
        float e = 0.f;
        if (tid < 197) { e = expf(sc[tid] - m); sc[tid] = e; }
        red[tid] = e;
        __syncthreads();
        for (int off = 128; off > 0; off >>= 1) {
            if (tid < off) red[tid] += red[tid + off];
            __syncthreads();
        }
        float inv = 1.f / red[0];
        if (tid >= 1 && tid < 197) ah[tid - 1] += sc[tid] * inv;
    }
    __syncthreads();
    for (int j = tid; j < 196; j += 256) Ahat[(size_t)b * 196 + j] = ah[j];
}

__global__ __launch_bounds__(256) void zo_k(
    const float* __restrict__ t, const float* __restrict__ impw,
    const float* __restrict__ impb, const float* __restrict__ Ahat,
    float* __restrict__ O)
{
    int b = blockIdx.x, tid = threadIdx.x;
    __shared__ float w[768];
    w[tid] = impw[tid]; w[tid + 256] = impw[tid + 256]; w[tid + 512] = impw[tid + 512];
    __syncthreads();
    for (int j = tid; j < 196; j += 256) {
        const float* tr = t + ((size_t)(b * 197) + 1 + j) * 768;
        float acc = impb[0];
        for (int d = 0; d < 768; ++d) acc += tr[d] * w[d];
        float z = 1.f / (1.f + expf(-acc));
        float a = Ahat[(size_t)b * 196 + j];
        O[(size_t)b * 196 + j] = a + a * z;
    }
}

// exact jax.lax.top_k semantics: descending, ties -> lower index first
__global__ __launch_bounds__(256) void topk_k(const float* __restrict__ O, int* __restrict__ idx)
{
    int b = blockIdx.x, tid = threadIdx.x;
    __shared__ float s[196];
    if (tid < 196) s[tid] = O[(size_t)b * 196 + tid];
    __syncthreads();
    if (tid < 196) {
        float v = s[tid];
        int rank = 0;
        for (int i = 0; i < 196; ++i) {
            float u = s[i];
            rank += (u > v) || (u == v && i < tid);
        }
        if (rank < 100) idx[b * 100 + rank] = tid;
    }
}

__global__ __launch_bounds__(256) void build_k(
    const float* __restrict__ t, const float* __restrict__ pos,
    const int* __restrict__ idx, float* __restrict__ inp, float* __restrict__ tp)
{
    int m = blockIdx.x, b = blockIdx.y, tid = threadIdx.x;
    float* dst = inp + ((size_t)(b * 101 + m)) * 768;
    if (m == 0) {
        const float* tr = t + (size_t)b * 197 * 768;
        for (int e = tid; e < 768; e += 256) dst[e] = tr[e] + pos[e];
    } else {
        int j = idx[b * 100 + m - 1];
        const float* tr = t + ((size_t)(b * 197) + 1 + j) * 768;
        const float* pr = pos + (size_t)(1 + j) * 768;
        float* tpr = tp + ((size_t)(b * 100) + (m - 1)) * 768;
        for (int e = tid; e < 768; e += 256) {
            float val = tr[e];
            tpr[e] = val;
            dst[e] = val + pr[e];
        }
    }
}

// ---------------- host side ----------------
extern "C" void kernel_launch(void* const* d_in, const int* in_sizes, int n_in,
                              void* d_out, int out_size, void* d_ws, size_t ws_size,
                              hipStream_t stream)
{
    const float* x      = (const float*)d_in[0];
    const float* conv_w = (const float*)d_in[1];
    const float* conv_b = (const float*)d_in[2];
    const float* cls    = (const float*)d_in[3];
    const float* pos    = (const float*)d_in[4];
    const float* ln1_s  = (const float*)d_in[5];
    const float* ln1_b  = (const float*)d_in[6];
    const float* qkv_w  = (const float*)d_in[7];
    const float* qkv_b  = (const float*)d_in[8];
    const float* proj_w = (const float*)d_in[9];
    const float* proj_b = (const float*)d_in[10];
    const float* ln2_s  = (const float*)d_in[11];
    const float* ln2_b  = (const float*)d_in[12];
    const float* mlp_w1 = (const float*)d_in[13];
    const float* mlp_b1 = (const float*)d_in[14];
    const float* mlp_w2 = (const float*)d_in[15];
    const float* mlp_b2 = (const float*)d_in[16];
    const float* fln_s  = (const float*)d_in[17];
    const float* fln_b  = (const float*)d_in[18];
    const float* imp_w  = (const float*)d_in[19];
    const float* imp_b  = (const float*)d_in[20];

    const size_t SZ_T = (size_t)32 * 197 * 768;   // 4,841,472 el
    const size_t SZ_H = (size_t)32 * 197 * 3072;  // 19,365,888 el
    const size_t SZ_W = (size_t)768 * 3072;       // 2,359,296 el

    // byte-cursor workspace layout (phase-aliased big scratch), total ~189 MB
    char* p = (char*)d_ws;
    auto alloc = [&](size_t bytes) { char* r = p; p += (bytes + 255) & ~(size_t)255; return r; };
    float* T   = (float*)alloc(SZ_T * 4);
    float* INP = (float*)alloc((size_t)32 * 101 * 768 * 4);
    float* Q0  = (float*)alloc(24576 * 4);
    float* AH  = (float*)alloc(6272 * 4);
    float* OV  = (float*)alloc(6272 * 4);
    int*   IDX = (int*)alloc(3200 * 4);
    short* Yh  = (short*)alloc(SZ_T * 2);
    short* Ym  = (short*)alloc(SZ_T * 2);
    short* Yl  = (short*)alloc(SZ_T * 2);
    short* Wh  = (short*)alloc(SZ_W * 2);
    short* Wm  = (short*)alloc(SZ_W * 2);
    short* Wl  = (short*)alloc(SZ_W * 2);
    char*  S   = alloc((size_t)116195328);  // max(QKV 58.1MB + OB 29.0MB, H 116.2MB)
    // phase 1 (attn): QKV fp32 + OB triple
    float* QKV = (float*)S;
    short* OBh = (short*)(S + (size_t)58097664);
    short* OBm = OBh + SZ_T;
    short* OBl = OBm + SZ_T;
    // phase 2 (mlp): H triple overlays everything in S
    short* Hh = (short*)S;
    short* Hm = Hh + SZ_H;
    short* Hl = Hm + SZ_H;

    float* out0 = (float*)d_out;                        // (32,101,768)
    float* out1 = out0 + (size_t)32 * 101 * 768;        // top_patches (32,100,768)

    auto cvt = [&](const float* W, int K, int N, int ld) {
        ts_k<<<dim3(N / 32, K / 32), 256, 0, stream>>>(W, ld, Wh, Wm, Wl, K, N);
    };

    // ---- patch embed ----
    esplit_k<<<(768 * 768) / 256, 256, 0, stream>>>(conv_w, Wh, Wm, Wl, 768 * 768); // conv_w already [n][k]
    gather_k<<<dim3(196, 32), 256, 0, stream>>>(x, Yh, Ym, Yl);
    mgemm_k<0><<<dim3(6, 49), 256, 0, stream>>>(Yh, Ym, Yl, Wh, Wm, Wl, conv_b, nullptr,
                                                QKV, nullptr, nullptr, nullptr, 6272, 768, 768, 768);
    embed_k<<<dim3(197, 32), 256, 0, stream>>>(QKV, cls, pos, T);

    auto run_block = [&](float* X, int L, int i) {
        int M = 32 * L;
        int mt = (M + 127) / 128;
        int sblk = (L + 7) / 8;
        ln_k<1><<<M, 256, 0, stream>>>(X, ln1_s + i * 768, ln1_b + i * 768, nullptr, Yh, Ym, Yl);
        cvt(qkv_w + (size_t)i * 768 * 2304, 768, 2304, 2304);
        mgemm_k<0><<<dim3(18, mt), 256, 0, stream>>>(Yh, Ym, Yl, Wh, Wm, Wl, qkv_b + (size_t)i * 2304,
                                                     nullptr, QKV, nullptr, nullptr, nullptr, M, 2304, 768, 2304);
        attn_k<<<dim3(sblk, NHEAD, 32), 256, 0, stream>>>(QKV, OBh, OBm, OBl, L);
        cvt(proj_w + (size_t)i * 768 * 768, 768, 768, 768);
        mgemm_k<1><<<dim3(6, mt), 256, 0, stream>>>(OBh, OBm, OBl, Wh, Wm, Wl, proj_b + (size_t)i * 768,
                                                    X, X, nullptr, nullptr, nullptr, M, 768, 768, 768);
        ln_k<1><<<M, 256, 0, stream>>>(X, ln2_s + i * 768, ln2_b + i * 768, nullptr, Yh, Ym, Yl);
        cvt(mlp_w1 + (size_t)i * 768 * 3072, 768, 3072, 3072);
        mgemm_k<2><<<dim3(24, mt), 256, 0, stream>>>(Yh, Ym, Yl, Wh, Wm, Wl, mlp_b1 + (size_t)i * 3072,
                                                     nullptr, nullptr, Hh, Hm, Hl, M, 3072, 768, 3072);
        cvt(mlp_w2 + (size_t)i * 3072 * 768, 3072, 768, 768);
        mgemm_k<1><<<dim3(6, mt), 256, 0, stream>>>(Hh, Hm, Hl, Wh, Wm, Wl, mlp_b2 + (size_t)i * 768,
                                                    X, X, nullptr, nullptr, nullptr, M, 768, 3072, 768);
    };

    for (int i = 0; i < 11; ++i) run_block(T, 197, i);

    // ---- A_hat: layer-10 attention weights on RAW t (no LN), q-row 0 only ----
    esplit_k<<<(int)(SZ_T / 256), 256, 0, stream>>>(T, Yh, Ym, Yl, (int)SZ_T);
    cvt(qkv_w + (size_t)10 * 768 * 2304 + 768, 768, 768, 2304);     // K-slice of qkv_w[10]
    mgemm_k<0><<<dim3(6, 50), 256, 0, stream>>>(Yh, Ym, Yl, Wh, Wm, Wl, qkv_b + (size_t)10 * 2304 + 768,
                                                nullptr, QKV, nullptr, nullptr, nullptr, 6304, 768, 768, 768);
    q0_k<<<32, 256, 0, stream>>>(T, qkv_w + (size_t)10 * 768 * 2304, qkv_b + (size_t)10 * 2304, Q0);
    ahat_k<<<32, 256, 0, stream>>>(QKV, Q0, AH);
    zo_k<<<32, 256, 0, stream>>>(T, imp_w, imp_b, AH, OV);
    topk_k<<<32, 256, 0, stream>>>(OV, IDX);
    build_k<<<dim3(101, 32), 256, 0, stream>>>(T, pos, IDX, INP, out1);

    // ---- last block on gathered tokens (L=101, layer 11) ----
    run_block(INP, 101, 11);

    // ---- final LN -> out0 ----
    ln_k<0><<<32 * 101, 256, 0, stream>>>(INP, fln_s, fln_b, out0, nullptr, nullptr, nullptr);

    (void)in_sizes; (void)n_in; (void)out_size; (void)ws_size;
}